// Round 1
// baseline (93.319 us; speedup 1.0000x reference)
//
#include <hip/hip_runtime.h>
#include <math.h>

#define NF 50
#define REC 52   // per-block record: 50 z + m + s

// tanh(x) = 1 - 2/(e^{2x}+1); handles +-inf gracefully via rcp(inf)=0
__device__ __forceinline__ float fast_tanh(float x) {
    float e = __expf(2.0f * x);
    float r = __builtin_amdgcn_rcpf(e + 1.0f);
    return 1.0f - 2.0f * r;
}

// Pass 1: flash-style online softmax-weighted sum.
// 16 lanes per row: lane j holds feature pairs (2j,2j+1) [j<13] and
// (26+2j,27+2j) [j<12]. 256 threads = 16 groups/block.
__global__ __launch_bounds__(256) void attn_pass1(
    const float* __restrict__ query, const float* __restrict__ ql_w,
    const float* __restrict__ qWp, float* __restrict__ ws,
    int T, int totalGroups)
{
    const float qW = qWp[0];
    const int tid  = threadIdx.x;
    const int j    = tid & 15;        // lane within group
    const int gIn  = tid >> 4;        // group within block [0,16)
    const int gGlob = blockIdx.x * 16 + gIn;

    float wA0 = 0.f, wA1 = 0.f, wB0 = 0.f, wB1 = 0.f;
    if (j < 13) { wA0 = ql_w[2*j];     wA1 = ql_w[2*j+1]; }
    if (j < 12) { wB0 = ql_w[26+2*j];  wB1 = ql_w[27+2*j]; }

    float m = -1e30f, s = 0.0f;
    float z0 = 0.f, z1 = 0.f, z2 = 0.f, z3 = 0.f;

    for (int row = gGlob; row < T; row += totalGroups) {
        const float2* qp = (const float2*)(query + (size_t)row * NF);
        float2 a = make_float2(0.f, 0.f), b = make_float2(0.f, 0.f);
        if (j < 13) a = qp[j];
        if (j < 12) b = qp[13 + j];

        float t0 = fast_tanh(qW * a.x);
        float t1 = fast_tanh(qW * a.y);
        float t2 = fast_tanh(qW * b.x);
        float t3 = fast_tanh(qW * b.y);
        float part = t0*wA0 + t1*wA1 + t2*wB0 + t3*wB1;
        part += __shfl_xor(part, 1);
        part += __shfl_xor(part, 2);
        part += __shfl_xor(part, 4);
        part += __shfl_xor(part, 8);
        const float score = part;   // uniform across the 16-lane group

        float mn = fmaxf(m, score);
        float c  = __expf(m - mn);       // ==1 unless new max
        float p  = __expf(score - mn);
        s  = s * c + p;
        z0 = fmaf(p, a.x, z0 * c);
        z1 = fmaf(p, a.y, z1 * c);
        z2 = fmaf(p, b.x, z2 * c);
        z3 = fmaf(p, b.y, z3 * c);
        m = mn;
    }

    __shared__ float sm[16], ss[16];
    __shared__ float sz[16][REC];
    if (j == 0) { sm[gIn] = m; ss[gIn] = s; }
    if (j < 13) { sz[gIn][2*j]    = z0; sz[gIn][2*j+1]  = z1; }
    if (j < 12) { sz[gIn][26+2*j] = z2; sz[gIn][27+2*j] = z3; }
    __syncthreads();

    if (tid < NF) {
        float M = sm[0];
        #pragma unroll
        for (int h = 1; h < 16; ++h) M = fmaxf(M, sm[h]);
        float S = 0.f, Z = 0.f;
        #pragma unroll
        for (int h = 0; h < 16; ++h) {
            float e = __expf(sm[h] - M);
            S += ss[h] * e;
            Z += sz[h][tid] * e;
        }
        float* rec = ws + (size_t)blockIdx.x * REC;
        rec[tid] = Z;
        if (tid == 0) { rec[50] = M; rec[51] = S; }
    }
}

// Pass 2: merge B block records -> out[50]
__global__ __launch_bounds__(256) void attn_pass2(
    const float* __restrict__ ws, float* __restrict__ out, int B)
{
    __shared__ float e_lds[2048];
    __shared__ float red[256];
    __shared__ float zred[4][64];
    __shared__ float Ssh;
    const int tid = threadIdx.x;

    // global max of block maxima
    float M = -1e30f;
    for (int b = tid; b < B; b += 256) M = fmaxf(M, ws[(size_t)b*REC + 50]);
    red[tid] = M;
    __syncthreads();
    for (int st = 128; st > 0; st >>= 1) {
        if (tid < st) red[tid] = fmaxf(red[tid], red[tid + st]);
        __syncthreads();
    }
    M = red[0];
    __syncthreads();

    // scale factors + global denominator
    float Sp = 0.f;
    for (int b = tid; b < B; b += 256) {
        float e = __expf(ws[(size_t)b*REC + 50] - M);
        e_lds[b] = e;
        Sp += ws[(size_t)b*REC + 51] * e;
    }
    red[tid] = Sp;
    __syncthreads();
    for (int st = 128; st > 0; st >>= 1) {
        if (tid < st) red[tid] += red[tid + st];
        __syncthreads();
    }
    if (tid == 0) Ssh = red[0];
    __syncthreads();

    // numerator: threads (f, chunk c) accumulate over strided blocks
    const int f = tid & 63, c = tid >> 6;
    float Zp = 0.f;
    if (f < NF) {
        for (int b = c; b < B; b += 4) Zp += ws[(size_t)b*REC + f] * e_lds[b];
    }
    zred[c][f] = Zp;
    __syncthreads();
    if (tid < NF) {
        float Z = zred[0][tid] + zred[1][tid] + zred[2][tid] + zred[3][tid];
        out[tid] = Z / Ssh;
    }
}

extern "C" void kernel_launch(void* const* d_in, const int* in_sizes, int n_in,
                              void* d_out, int out_size, void* d_ws, size_t ws_size,
                              hipStream_t stream) {
    const float* query = (const float*)d_in[0];
    const float* ql_w  = (const float*)d_in[1];
    const float* qW    = (const float*)d_in[2];
    float* out = (float*)d_out;
    float* ws  = (float*)d_ws;

    const int T = in_sizes[0] / NF;

    int B = 1024;
    size_t need = (size_t)B * REC * sizeof(float);
    if (ws_size < need) {
        B = (int)(ws_size / (REC * sizeof(float)));
        if (B < 1) B = 1;
    }
    if (B > 2048) B = 2048;

    const int totalGroups = B * 16;
    hipLaunchKernelGGL(attn_pass1, dim3(B), dim3(256), 0, stream,
                       query, ql_w, qW, ws, T, totalGroups);
    hipLaunchKernelGGL(attn_pass2, dim3(1), dim3(256), 0, stream,
                       ws, out, B);
}

// Round 2
// 34.243 us; speedup vs baseline: 2.7252x; 2.7252x over previous
//
#include <hip/hip_runtime.h>
#include <math.h>

#define NF 50
#define REC 52   // per-block record: 50 z + m + s
#define NBLK 1024

// tanh(x) = 1 - 2/(e^{2x}+1); handles +-inf gracefully via rcp(inf)=0
__device__ __forceinline__ float fast_tanh(float x) {
    float e = __expf(2.0f * x);
    float r = __builtin_amdgcn_rcpf(e + 1.0f);
    return 1.0f - 2.0f * r;
}

// Pass 1: flash-style online softmax-weighted sum.
// 16 lanes per row: lane j holds feature pairs (2j,2j+1) [j<13] and
// (26+2j,27+2j) [j<12]. 256 threads = 16 groups/block.
// 2 rows per iteration for ILP; single fused rescale per pair.
__global__ __launch_bounds__(256) void attn_pass1(
    const float* __restrict__ query, const float* __restrict__ ql_w,
    const float* __restrict__ qWp, float* __restrict__ ws,
    int T, int totalGroups)
{
    const float qW = qWp[0];
    const int tid  = threadIdx.x;
    const int j    = tid & 15;        // lane within group
    const int gIn  = tid >> 4;        // group within block [0,16)
    const int gGlob = blockIdx.x * 16 + gIn;

    float wA0 = 0.f, wA1 = 0.f, wB0 = 0.f, wB1 = 0.f;
    if (j < 13) { wA0 = ql_w[2*j];     wA1 = ql_w[2*j+1]; }
    if (j < 12) { wB0 = ql_w[26+2*j];  wB1 = ql_w[27+2*j]; }

    float m = -1e30f, s = 0.0f;
    float z0 = 0.f, z1 = 0.f, z2 = 0.f, z3 = 0.f;

    const int stride = totalGroups;
    int row = gGlob;
    for (; row + stride < T; row += 2 * stride) {
        const float2* q0 = (const float2*)(query + (size_t)row * NF);
        const float2* q1 = (const float2*)(query + (size_t)(row + stride) * NF);
        float2 a0 = make_float2(0.f,0.f), b0 = make_float2(0.f,0.f);
        float2 a1 = make_float2(0.f,0.f), b1 = make_float2(0.f,0.f);
        if (j < 13) { a0 = q0[j];     a1 = q1[j]; }
        if (j < 12) { b0 = q0[13+j];  b1 = q1[13+j]; }

        float p0 = fast_tanh(qW*a0.x)*wA0 + fast_tanh(qW*a0.y)*wA1
                 + fast_tanh(qW*b0.x)*wB0 + fast_tanh(qW*b0.y)*wB1;
        float p1 = fast_tanh(qW*a1.x)*wA0 + fast_tanh(qW*a1.y)*wA1
                 + fast_tanh(qW*b1.x)*wB0 + fast_tanh(qW*b1.y)*wB1;
        p0 += __shfl_xor(p0, 1);  p1 += __shfl_xor(p1, 1);
        p0 += __shfl_xor(p0, 2);  p1 += __shfl_xor(p1, 2);
        p0 += __shfl_xor(p0, 4);  p1 += __shfl_xor(p1, 4);
        p0 += __shfl_xor(p0, 8);  p1 += __shfl_xor(p1, 8);
        const float sc0 = p0, sc1 = p1;

        float mn = fmaxf(fmaxf(m, sc0), sc1);
        float c  = __expf(m - mn);
        float e0 = __expf(sc0 - mn);
        float e1 = __expf(sc1 - mn);
        s  = fmaf(s, c, e0 + e1);
        z0 = fmaf(e0, a0.x, fmaf(e1, a1.x, z0 * c));
        z1 = fmaf(e0, a0.y, fmaf(e1, a1.y, z1 * c));
        z2 = fmaf(e0, b0.x, fmaf(e1, b1.x, z2 * c));
        z3 = fmaf(e0, b0.y, fmaf(e1, b1.y, z3 * c));
        m = mn;
    }
    if (row < T) {
        const float2* q0 = (const float2*)(query + (size_t)row * NF);
        float2 a0 = make_float2(0.f,0.f), b0 = make_float2(0.f,0.f);
        if (j < 13) a0 = q0[j];
        if (j < 12) b0 = q0[13+j];
        float p0 = fast_tanh(qW*a0.x)*wA0 + fast_tanh(qW*a0.y)*wA1
                 + fast_tanh(qW*b0.x)*wB0 + fast_tanh(qW*b0.y)*wB1;
        p0 += __shfl_xor(p0, 1);
        p0 += __shfl_xor(p0, 2);
        p0 += __shfl_xor(p0, 4);
        p0 += __shfl_xor(p0, 8);
        float mn = fmaxf(m, p0);
        float c  = __expf(m - mn);
        float e0 = __expf(p0 - mn);
        s  = fmaf(s, c, e0);
        z0 = fmaf(e0, a0.x, z0 * c);
        z1 = fmaf(e0, a0.y, z1 * c);
        z2 = fmaf(e0, b0.x, z2 * c);
        z3 = fmaf(e0, b0.y, z3 * c);
        m = mn;
    }

    __shared__ float sm[16], ss[16];
    __shared__ float sz[16][REC];
    if (j == 0) { sm[gIn] = m; ss[gIn] = s; }
    if (j < 13) { sz[gIn][2*j]    = z0; sz[gIn][2*j+1]  = z1; }
    if (j < 12) { sz[gIn][26+2*j] = z2; sz[gIn][27+2*j] = z3; }
    __syncthreads();

    if (tid < NF) {
        float M = sm[0];
        #pragma unroll
        for (int h = 1; h < 16; ++h) M = fmaxf(M, sm[h]);
        float S = 0.f, Z = 0.f;
        #pragma unroll
        for (int h = 0; h < 16; ++h) {
            float e = __expf(sm[h] - M);
            S += ss[h] * e;
            Z += sz[h][tid] * e;
        }
        float* rec = ws + (size_t)blockIdx.x * REC;
        rec[tid] = Z;
        if (tid == 0) { rec[50] = M; rec[51] = S; }
    }
}

// Pass 2: merge B block records -> out[50].
// 1024 threads = 16 waves. Phase A: coalesced (m,s) float2 loads + block
// reductions. Phase B: wave w handles records b = w, w+16, ...; lanes 0..51
// read one contiguous record slice (coalesced), 4-way unrolled.
__global__ __launch_bounds__(1024) void attn_pass2(
    const float* __restrict__ ws, float* __restrict__ out, int B)
{
    __shared__ float e_lds[NBLK];
    __shared__ float red[1024];
    __shared__ float zacc[16][REC];
    const int tid = threadIdx.x;

    // Phase A: per-record (m, s)
    float mv = -1e30f, sv = 0.f;
    if (tid < B) {
        float2 ms = *(const float2*)(ws + (size_t)tid * REC + 50);
        mv = ms.x; sv = ms.y;
    }
    red[tid] = mv;
    __syncthreads();
    #pragma unroll
    for (int st = 512; st > 0; st >>= 1) {
        if (tid < st) red[tid] = fmaxf(red[tid], red[tid + st]);
        __syncthreads();
    }
    const float M = red[0];
    __syncthreads();

    float e = __expf(mv - M);          // 0 for inactive slots
    e_lds[tid] = e;
    red[tid] = sv * e;
    __syncthreads();
    #pragma unroll
    for (int st = 512; st > 0; st >>= 1) {
        if (tid < st) red[tid] += red[tid + st];
        __syncthreads();
    }
    const float S = red[0];

    // Phase B: numerator
    const int w = tid >> 6, lane = tid & 63;
    float acc = 0.f;
    if (lane < REC) {
        int b = w;
        for (; b + 48 < B; b += 64) {
            float v0 = ws[(size_t)(b     ) * REC + lane];
            float v1 = ws[(size_t)(b + 16) * REC + lane];
            float v2 = ws[(size_t)(b + 32) * REC + lane];
            float v3 = ws[(size_t)(b + 48) * REC + lane];
            acc += v0 * e_lds[b] + v1 * e_lds[b + 16]
                 + v2 * e_lds[b + 32] + v3 * e_lds[b + 48];
        }
        for (; b < B; b += 16)
            acc += ws[(size_t)b * REC + lane] * e_lds[b];
        zacc[w][lane] = acc;
    }
    __syncthreads();
    if (tid < NF) {
        float Z = 0.f;
        #pragma unroll
        for (int h = 0; h < 16; ++h) Z += zacc[h][tid];
        out[tid] = Z / S;
    }
}

extern "C" void kernel_launch(void* const* d_in, const int* in_sizes, int n_in,
                              void* d_out, int out_size, void* d_ws, size_t ws_size,
                              hipStream_t stream) {
    const float* query = (const float*)d_in[0];
    const float* ql_w  = (const float*)d_in[1];
    const float* qW    = (const float*)d_in[2];
    float* out = (float*)d_out;
    float* ws  = (float*)d_ws;

    const int T = in_sizes[0] / NF;

    int B = NBLK;
    size_t need = (size_t)B * REC * sizeof(float);
    if (ws_size < need) {
        B = (int)(ws_size / (REC * sizeof(float)));
        if (B < 1) B = 1;
    }

    const int totalGroups = B * 16;
    hipLaunchKernelGGL(attn_pass1, dim3(B), dim3(256), 0, stream,
                       query, ql_w, qW, ws, T, totalGroups);
    hipLaunchKernelGGL(attn_pass2, dim3(1), dim3(1024), 0, stream,
                       ws, out, B);
}

// Round 3
// 31.264 us; speedup vs baseline: 2.9849x; 1.0953x over previous
//
#include <hip/hip_runtime.h>
#include <math.h>

#define NF 50
#define REC 52   // per-block record: 50 z + m + s
#define NBLK 1024
#define GRP_PER_BLK 32   // 512 threads = 32 groups of 16 lanes

// tanh(x) = 1 - 2/(e^{2x}+1); handles +-inf gracefully via rcp(inf)=0
__device__ __forceinline__ float fast_tanh(float x) {
    float e = __expf(2.0f * x);
    float r = __builtin_amdgcn_rcpf(e + 1.0f);
    return 1.0f - 2.0f * r;
}

// Pass 1: flash-style online softmax-weighted sum.
// 16 lanes per row: lane j holds feature pairs (2j,2j+1) [j<13] and
// (26+2j,27+2j) [j<12]. 512 threads = 32 groups/block -> 8 waves/SIMD
// occupancy (latency hiding), VGPR capped at 64 via launch_bounds.
__global__ __launch_bounds__(512, 8) void attn_pass1(
    const float* __restrict__ query, const float* __restrict__ ql_w,
    const float* __restrict__ qWp, float* __restrict__ ws,
    int T, int totalGroups)
{
    const float qW = qWp[0];
    const int tid  = threadIdx.x;
    const int j    = tid & 15;        // lane within group
    const int gIn  = tid >> 4;        // group within block [0,32)
    const int gGlob = blockIdx.x * GRP_PER_BLK + gIn;

    float wA0 = 0.f, wA1 = 0.f, wB0 = 0.f, wB1 = 0.f;
    if (j < 13) { wA0 = ql_w[2*j];     wA1 = ql_w[2*j+1]; }
    if (j < 12) { wB0 = ql_w[26+2*j];  wB1 = ql_w[27+2*j]; }

    float m = -1e30f, s = 0.0f;
    float z0 = 0.f, z1 = 0.f, z2 = 0.f, z3 = 0.f;

    const int stride = totalGroups;
    int row = gGlob;
    for (; row + stride < T; row += 2 * stride) {
        const float2* q0 = (const float2*)(query + (size_t)row * NF);
        const float2* q1 = (const float2*)(query + (size_t)(row + stride) * NF);
        float2 a0 = make_float2(0.f,0.f), b0 = make_float2(0.f,0.f);
        float2 a1 = make_float2(0.f,0.f), b1 = make_float2(0.f,0.f);
        if (j < 13) { a0 = q0[j];     a1 = q1[j]; }
        if (j < 12) { b0 = q0[13+j];  b1 = q1[13+j]; }

        float p0 = fmaf(fast_tanh(qW*a0.x), wA0, fmaf(fast_tanh(qW*a0.y), wA1,
                   fmaf(fast_tanh(qW*b0.x), wB0, fast_tanh(qW*b0.y)*wB1)));
        float p1 = fmaf(fast_tanh(qW*a1.x), wA0, fmaf(fast_tanh(qW*a1.y), wA1,
                   fmaf(fast_tanh(qW*b1.x), wB0, fast_tanh(qW*b1.y)*wB1)));
        p0 += __shfl_xor(p0, 1);  p1 += __shfl_xor(p1, 1);
        p0 += __shfl_xor(p0, 2);  p1 += __shfl_xor(p1, 2);
        p0 += __shfl_xor(p0, 4);  p1 += __shfl_xor(p1, 4);
        p0 += __shfl_xor(p0, 8);  p1 += __shfl_xor(p1, 8);
        const float sc0 = p0, sc1 = p1;

        float mn = fmaxf(fmaxf(m, sc0), sc1);
        float c  = __expf(m - mn);
        float e0 = __expf(sc0 - mn);
        float e1 = __expf(sc1 - mn);
        s  = fmaf(s, c, e0 + e1);
        z0 = fmaf(e0, a0.x, fmaf(e1, a1.x, z0 * c));
        z1 = fmaf(e0, a0.y, fmaf(e1, a1.y, z1 * c));
        z2 = fmaf(e0, b0.x, fmaf(e1, b1.x, z2 * c));
        z3 = fmaf(e0, b0.y, fmaf(e1, b1.y, z3 * c));
        m = mn;
    }
    if (row < T) {
        const float2* q0 = (const float2*)(query + (size_t)row * NF);
        float2 a0 = make_float2(0.f,0.f), b0 = make_float2(0.f,0.f);
        if (j < 13) a0 = q0[j];
        if (j < 12) b0 = q0[13+j];
        float p0 = fmaf(fast_tanh(qW*a0.x), wA0, fmaf(fast_tanh(qW*a0.y), wA1,
                   fmaf(fast_tanh(qW*b0.x), wB0, fast_tanh(qW*b0.y)*wB1)));
        p0 += __shfl_xor(p0, 1);
        p0 += __shfl_xor(p0, 2);
        p0 += __shfl_xor(p0, 4);
        p0 += __shfl_xor(p0, 8);
        float mn = fmaxf(m, p0);
        float c  = __expf(m - mn);
        float e0 = __expf(p0 - mn);
        s  = fmaf(s, c, e0);
        z0 = fmaf(e0, a0.x, z0 * c);
        z1 = fmaf(e0, a0.y, z1 * c);
        z2 = fmaf(e0, b0.x, z2 * c);
        z3 = fmaf(e0, b0.y, z3 * c);
        m = mn;
    }

    __shared__ float sm[GRP_PER_BLK], ss[GRP_PER_BLK];
    __shared__ float sz[GRP_PER_BLK][REC];
    if (j == 0) { sm[gIn] = m; ss[gIn] = s; }
    if (j < 13) { sz[gIn][2*j]    = z0; sz[gIn][2*j+1]  = z1; }
    if (j < 12) { sz[gIn][26+2*j] = z2; sz[gIn][27+2*j] = z3; }
    __syncthreads();

    if (tid < NF) {
        float M = sm[0];
        #pragma unroll
        for (int h = 1; h < GRP_PER_BLK; ++h) M = fmaxf(M, sm[h]);
        float S = 0.f, Z = 0.f;
        #pragma unroll
        for (int h = 0; h < GRP_PER_BLK; ++h) {
            float e = __expf(sm[h] - M);
            S += ss[h] * e;
            Z += sz[h][tid] * e;
        }
        float* rec = ws + (size_t)blockIdx.x * REC;
        rec[tid] = Z;
        if (tid == 0) { rec[50] = M; rec[51] = S; }
    }
}

// Pass 2: merge B block records -> out[50].
// 1024 threads = 16 waves. Phase A: coalesced (m,s) float2 loads + block
// reductions. Phase B: wave w handles records b = w, w+16, ...; lanes 0..51
// read one contiguous record slice (coalesced), 8-way unrolled.
__global__ __launch_bounds__(1024) void attn_pass2(
    const float* __restrict__ ws, float* __restrict__ out, int B)
{
    __shared__ float e_lds[NBLK];
    __shared__ float red[1024];
    __shared__ float zacc[16][REC];
    const int tid = threadIdx.x;

    // Phase A: per-record (m, s)
    float mv = -1e30f, sv = 0.f;
    if (tid < B) {
        float2 ms = *(const float2*)(ws + (size_t)tid * REC + 50);
        mv = ms.x; sv = ms.y;
    }
    red[tid] = mv;
    __syncthreads();
    #pragma unroll
    for (int st = 512; st > 0; st >>= 1) {
        if (tid < st) red[tid] = fmaxf(red[tid], red[tid + st]);
        __syncthreads();
    }
    const float M = red[0];
    __syncthreads();

    float e = __expf(mv - M);          // 0 for inactive slots
    e_lds[tid] = e;
    red[tid] = sv * e;
    __syncthreads();
    #pragma unroll
    for (int st = 512; st > 0; st >>= 1) {
        if (tid < st) red[tid] += red[tid + st];
        __syncthreads();
    }
    const float S = red[0];

    // Phase B: numerator
    const int w = tid >> 6, lane = tid & 63;
    float acc = 0.f;
    if (lane < REC) {
        int b = w;
        for (; b + 112 < B; b += 128) {
            float v0 = ws[(size_t)(b      ) * REC + lane];
            float v1 = ws[(size_t)(b +  16) * REC + lane];
            float v2 = ws[(size_t)(b +  32) * REC + lane];
            float v3 = ws[(size_t)(b +  48) * REC + lane];
            float v4 = ws[(size_t)(b +  64) * REC + lane];
            float v5 = ws[(size_t)(b +  80) * REC + lane];
            float v6 = ws[(size_t)(b +  96) * REC + lane];
            float v7 = ws[(size_t)(b + 112) * REC + lane];
            acc += v0 * e_lds[b]      + v1 * e_lds[b +  16]
                 + v2 * e_lds[b + 32] + v3 * e_lds[b +  48]
                 + v4 * e_lds[b + 64] + v5 * e_lds[b +  80]
                 + v6 * e_lds[b + 96] + v7 * e_lds[b + 112];
        }
        for (; b < B; b += 16)
            acc += ws[(size_t)b * REC + lane] * e_lds[b];
        zacc[w][lane] = acc;
    }
    __syncthreads();
    if (tid < NF) {
        float Z = 0.f;
        #pragma unroll
        for (int h = 0; h < 16; ++h) Z += zacc[h][tid];
        out[tid] = Z / S;
    }
}

extern "C" void kernel_launch(void* const* d_in, const int* in_sizes, int n_in,
                              void* d_out, int out_size, void* d_ws, size_t ws_size,
                              hipStream_t stream) {
    const float* query = (const float*)d_in[0];
    const float* ql_w  = (const float*)d_in[1];
    const float* qW    = (const float*)d_in[2];
    float* out = (float*)d_out;
    float* ws  = (float*)d_ws;

    const int T = in_sizes[0] / NF;

    int B = NBLK;
    size_t need = (size_t)B * REC * sizeof(float);
    if (ws_size < need) {
        B = (int)(ws_size / (REC * sizeof(float)));
        if (B < 1) B = 1;
    }

    const int totalGroups = B * GRP_PER_BLK;
    hipLaunchKernelGGL(attn_pass1, dim3(B), dim3(512), 0, stream,
                       query, ql_w, qW, ws, T, totalGroups);
    hipLaunchKernelGGL(attn_pass2, dim3(1), dim3(1024), 0, stream,
                       ws, out, B);
}

// Round 4
// 28.366 us; speedup vs baseline: 3.2899x; 1.1022x over previous
//
#include <hip/hip_runtime.h>
#include <math.h>

#define NF 50
#define REC 52   // per-block record: 50 z + s + pad
#define NBLK 1024
#define GRP_PER_BLK 32   // 512 threads = 32 groups of 16 lanes
#define LOG2E 1.44269504f

// All-lanes sum within each 16-lane DPP row via rotate butterfly:
// v += ror1(v); v += ror2(v); v += ror4(v); v += ror8(v)  -> every lane = row total.
__device__ __forceinline__ float row16_allsum(float v) {
    float t;
    t = __int_as_float(__builtin_amdgcn_update_dpp(0, __float_as_int(v), 0x121, 0xF, 0xF, true)); v += t; // row_ror:1
    t = __int_as_float(__builtin_amdgcn_update_dpp(0, __float_as_int(v), 0x122, 0xF, 0xF, true)); v += t; // row_ror:2
    t = __int_as_float(__builtin_amdgcn_update_dpp(0, __float_as_int(v), 0x124, 0xF, 0xF, true)); v += t; // row_ror:4
    t = __int_as_float(__builtin_amdgcn_update_dpp(0, __float_as_int(v), 0x128, 0xF, 0xF, true)); v += t; // row_ror:8
    return v;
}

// Per-lane partial of sum_f w_f / (e^{2 qW x_f} + 1)  (the r-part of w*tanh).
__device__ __forceinline__ float row_partial(float2 a, float2 b, float c2,
                                             float wA0, float wA1, float wB0, float wB1) {
    float r0 = __builtin_amdgcn_rcpf(__builtin_amdgcn_exp2f(c2 * a.x) + 1.f);
    float r1 = __builtin_amdgcn_rcpf(__builtin_amdgcn_exp2f(c2 * a.y) + 1.f);
    float r2 = __builtin_amdgcn_rcpf(__builtin_amdgcn_exp2f(c2 * b.x) + 1.f);
    float r3 = __builtin_amdgcn_rcpf(__builtin_amdgcn_exp2f(c2 * b.y) + 1.f);
    return fmaf(wA0, r0, fmaf(wA1, r1, fmaf(wB0, r2, wB1 * r3)));
}

// Pass 1: fixed-shift (no online max) softmax-weighted accumulation.
// score = sum_f w_f tanh(qW x_f) = sumW - 2 * sum_f w_f r_f
// e_row = exp(score - M0) = exp2( K - 2*log2e * rowsum(partial) )
// 16 lanes per row; 512 threads = 32 groups -> 8 waves/SIMD; 4-row unroll.
__global__ __launch_bounds__(512, 8) void attn_pass1(
    const float* __restrict__ query, const float* __restrict__ ql_w,
    const float* __restrict__ qWp, float* __restrict__ ws,
    int T, int totalGroups)
{
    const float qW = qWp[0];
    const int tid  = threadIdx.x;
    const int j    = tid & 15;
    const int gIn  = tid >> 4;
    const int gGlob = blockIdx.x * GRP_PER_BLK + gIn;

    float wA0 = 0.f, wA1 = 0.f, wB0 = 0.f, wB1 = 0.f;
    if (j < 13) { wA0 = ql_w[2*j];     wA1 = ql_w[2*j+1]; }
    if (j < 12) { wB0 = ql_w[26+2*j];  wB1 = ql_w[27+2*j]; }

    const float sumAbsW = row16_allsum(fabsf(wA0)+fabsf(wA1)+fabsf(wB0)+fabsf(wB1));
    const float sumW    = row16_allsum(wA0 + wA1 + wB0 + wB1);
    const float M0 = (sumAbsW > 80.f) ? (sumAbsW - 80.f) : 0.f;  // overflow guard; 0 here
    const float c2 = 2.f * qW * LOG2E;
    const float K  = (sumW - M0) * LOG2E;
    const float n2l = -2.f * LOG2E;

    float s = 0.f, z0 = 0.f, z1 = 0.f, z2 = 0.f, z3 = 0.f;

    const int stride = totalGroups;
    int row = gGlob;
    for (; row + 3*stride < T; row += 4*stride) {
        const float2* q0 = (const float2*)(query + (size_t)row * NF);
        const float2* q1 = (const float2*)(query + (size_t)(row +   stride) * NF);
        const float2* q2 = (const float2*)(query + (size_t)(row + 2*stride) * NF);
        const float2* q3 = (const float2*)(query + (size_t)(row + 3*stride) * NF);
        float2 a0 = make_float2(0.f,0.f), b0 = make_float2(0.f,0.f);
        float2 a1 = make_float2(0.f,0.f), b1 = make_float2(0.f,0.f);
        float2 a2 = make_float2(0.f,0.f), b2 = make_float2(0.f,0.f);
        float2 a3 = make_float2(0.f,0.f), b3 = make_float2(0.f,0.f);
        if (j < 13) { a0 = q0[j];    a1 = q1[j];    a2 = q2[j];    a3 = q3[j]; }
        if (j < 12) { b0 = q0[13+j]; b1 = q1[13+j]; b2 = q2[13+j]; b3 = q3[13+j]; }

        float p0 = row_partial(a0, b0, c2, wA0, wA1, wB0, wB1);
        float p1 = row_partial(a1, b1, c2, wA0, wA1, wB0, wB1);
        float p2 = row_partial(a2, b2, c2, wA0, wA1, wB0, wB1);
        float p3 = row_partial(a3, b3, c2, wA0, wA1, wB0, wB1);
        p0 = row16_allsum(p0);
        p1 = row16_allsum(p1);
        p2 = row16_allsum(p2);
        p3 = row16_allsum(p3);
        float e0 = __builtin_amdgcn_exp2f(fmaf(p0, n2l, K));
        float e1 = __builtin_amdgcn_exp2f(fmaf(p1, n2l, K));
        float e2 = __builtin_amdgcn_exp2f(fmaf(p2, n2l, K));
        float e3 = __builtin_amdgcn_exp2f(fmaf(p3, n2l, K));

        s += (e0 + e1) + (e2 + e3);
        z0 = fmaf(e0, a0.x, fmaf(e1, a1.x, fmaf(e2, a2.x, fmaf(e3, a3.x, z0))));
        z1 = fmaf(e0, a0.y, fmaf(e1, a1.y, fmaf(e2, a2.y, fmaf(e3, a3.y, z1))));
        z2 = fmaf(e0, b0.x, fmaf(e1, b1.x, fmaf(e2, b2.x, fmaf(e3, b3.x, z2))));
        z3 = fmaf(e0, b0.y, fmaf(e1, b1.y, fmaf(e2, b2.y, fmaf(e3, b3.y, z3))));
    }
    for (; row < T; row += stride) {
        const float2* q0 = (const float2*)(query + (size_t)row * NF);
        float2 a = make_float2(0.f,0.f), b = make_float2(0.f,0.f);
        if (j < 13) a = q0[j];
        if (j < 12) b = q0[13+j];
        float p = row_partial(a, b, c2, wA0, wA1, wB0, wB1);
        p = row16_allsum(p);
        float e = __builtin_amdgcn_exp2f(fmaf(p, n2l, K));
        s += e;
        z0 = fmaf(e, a.x, z0);
        z1 = fmaf(e, a.y, z1);
        z2 = fmaf(e, b.x, z2);
        z3 = fmaf(e, b.y, z3);
    }

    __shared__ float sz[GRP_PER_BLK][REC];
    if (j < 13) { sz[gIn][2*j]    = z0; sz[gIn][2*j+1]  = z1; }
    if (j < 12) { sz[gIn][26+2*j] = z2; sz[gIn][27+2*j] = z3; }
    if (j == 13) { sz[gIn][50] = s; sz[gIn][51] = 0.f; }
    __syncthreads();

    // per-block record = plain sum over the 32 groups (same shift everywhere)
    if (tid < 51) {
        float acc = 0.f;
        #pragma unroll
        for (int h = 0; h < GRP_PER_BLK; ++h) acc += sz[h][tid];
        ws[(size_t)blockIdx.x * REC + tid] = acc;
    }
}

// Pass 2: plain sum of B records (50 z + s each), divide, store.
__global__ __launch_bounds__(1024) void attn_pass2(
    const float* __restrict__ ws, float* __restrict__ out, int B)
{
    __shared__ float zacc[16][REC];
    const int tid = threadIdx.x;
    const int w = tid >> 6, lane = tid & 63;

    if (lane < 51) {
        float acc = 0.f;
        int b = w;
        for (; b + 112 < B; b += 128) {
            acc += ws[(size_t)(b      ) * REC + lane]
                 + ws[(size_t)(b +  16) * REC + lane]
                 + ws[(size_t)(b +  32) * REC + lane]
                 + ws[(size_t)(b +  48) * REC + lane]
                 + ws[(size_t)(b +  64) * REC + lane]
                 + ws[(size_t)(b +  80) * REC + lane]
                 + ws[(size_t)(b +  96) * REC + lane]
                 + ws[(size_t)(b + 112) * REC + lane];
        }
        for (; b < B; b += 16)
            acc += ws[(size_t)b * REC + lane];
        zacc[w][lane] = acc;
    }
    __syncthreads();
    if (tid < NF) {
        float Z = 0.f, S = 0.f;
        #pragma unroll
        for (int h = 0; h < 16; ++h) { Z += zacc[h][tid]; S += zacc[h][50]; }
        out[tid] = Z / S;
    }
}

extern "C" void kernel_launch(void* const* d_in, const int* in_sizes, int n_in,
                              void* d_out, int out_size, void* d_ws, size_t ws_size,
                              hipStream_t stream) {
    const float* query = (const float*)d_in[0];
    const float* ql_w  = (const float*)d_in[1];
    const float* qW    = (const float*)d_in[2];
    float* out = (float*)d_out;
    float* ws  = (float*)d_ws;

    const int T = in_sizes[0] / NF;

    int B = NBLK;
    size_t need = (size_t)B * REC * sizeof(float);
    if (ws_size < need) {
        B = (int)(ws_size / (REC * sizeof(float)));
        if (B < 1) B = 1;
    }

    const int totalGroups = B * GRP_PER_BLK;
    hipLaunchKernelGGL(attn_pass1, dim3(B), dim3(512), 0, stream,
                       query, ql_w, qW, ws, T, totalGroups);
    hipLaunchKernelGGL(attn_pass2, dim3(1), dim3(1024), 0, stream,
                       ws, out, B);
}